// Round 2
// baseline (1081.433 us; speedup 1.0000x reference)
//
#include <hip/hip_runtime.h>
#include <hip/hip_bf16.h>

typedef __attribute__((ext_vector_type(4))) float f32x4;
typedef __attribute__((ext_vector_type(8))) short bf16x8;

#define BM 128
#define BN 128
#define BK 32

__device__ __forceinline__ unsigned short f2bf(float f) {
  unsigned int u = __float_as_uint(f);
  u = (u + 0x7FFFu + ((u >> 16) & 1u)) >> 16;
  return (unsigned short)u;
}

__device__ __forceinline__ void gload16(const void* g, void* l) {
  __builtin_amdgcn_global_load_lds(
      (const __attribute__((address_space(1))) void*)g,
      (__attribute__((address_space(3))) void*)l,
      16, 0, 0);
}

// ---------------- fp32 -> bf16 convert (x only) ----------------
__global__ __launch_bounds__(256) void cvt_kernel(const float* __restrict__ in,
                                                  unsigned short* __restrict__ out,
                                                  int n4) {
  int i = blockIdx.x * 256 + threadIdx.x;
  const int stride = gridDim.x * 256;
  for (; i < n4; i += stride) {
    const float4 v = ((const float4*)in)[i];
    ushort4 o;
    o.x = f2bf(v.x); o.y = f2bf(v.y); o.z = f2bf(v.z); o.w = f2bf(v.w);
    ((ushort4*)out)[i] = o;
  }
}

// ---------------- routing: compact token indices per expert ----------------
__global__ __launch_bounds__(256) void route_kernel(const void* __restrict__ mask,
                                                    int n_tok,
                                                    int* __restrict__ idx_s,
                                                    int* __restrict__ idx_b,
                                                    int* __restrict__ counts) {
  __shared__ int mode_sh;
  __shared__ int cs[256], cb[256];
  __shared__ int os[256], ob[256];
  const unsigned char* mb = (const unsigned char*)mask;
  const int* mi = (const int*)mask;
  const int tid = threadIdx.x;
  if (tid == 0) mode_sh = 0;
  __syncthreads();
  int found = 0;
  for (int i = tid; i < n_tok; i += 256)
    if ((i & 3) == 1 && mb[i]) found = 1;   // int32/fp32 bools have byte1 == 0
  if (found) atomicOr(&mode_sh, 1);
  __syncthreads();
  const int byte_mode = mode_sh;
  const int per = n_tok / 256;
  const int t0 = tid * per;
  for (int i = 0; i < per; ++i) { idx_s[t0 + i] = 0; idx_b[t0 + i] = 0; }
  int ls = 0, lb = 0;
  for (int i = 0; i < per; ++i) {
    const int m = byte_mode ? (mb[t0 + i] != 0) : (mi[t0 + i] != 0);
    ls += !m; lb += m;
  }
  cs[tid] = ls; cb[tid] = lb;
  __syncthreads();
  if (tid == 0) {
    int as = 0, ab = 0;
    for (int i = 0; i < 256; ++i) { os[i] = as; ob[i] = ab; as += cs[i]; ab += cb[i]; }
    counts[0] = as; counts[1] = ab;
  }
  __syncthreads();
  int ps = os[tid], pb = ob[tid];
  for (int i = 0; i < per; ++i) {
    const int m = byte_mode ? (mb[t0 + i] != 0) : (mi[t0 + i] != 0);
    if (m) idx_b[pb++] = t0 + i; else idx_s[ps++] = t0 + i;
  }
}

// ---------------- GEMM1: H = gelu(gather(X) @ W^T + b), bf16 out ----------------
// X [n_tok,K] bf16 (gathered via idx); W [N,K] fp32 (torch [out,in]) converted
// to bf16 during LDS staging; H [CH,N] bf16 chunk-local.
__global__ __launch_bounds__(256) void gemm_fc_kernel(
    const unsigned short* __restrict__ X,
    const float* __restrict__ W,
    const float* __restrict__ bias,
    unsigned short* __restrict__ H,
    const int* __restrict__ idx,
    const int* __restrict__ cnt,
    const int rowbase, const int N, const int K) {
  __shared__ alignas(16) unsigned short As[BM * BK];
  __shared__ alignas(16) unsigned short Bs[BN * BK];
  const int M = *cnt;
  const int bn = blockIdx.x, bm = blockIdx.y;
  if (rowbase + bm * BM >= M) return;
  const int tid = threadIdx.x, wid = tid >> 6, lane = tid & 63;
  const int lr = lane & 15, lq = lane >> 4;
  // A staging (global_load_lds, 16B/lane, linear dest)
  const int srow = (wid << 5) + (lane >> 2);
  const int scol = (lane & 3) << 3;
  const int ga0 = idx[rowbase + bm * BM + srow];
  const int ga1 = idx[rowbase + bm * BM + srow + 16];
  const unsigned short* pA0 = X + (long)ga0 * K + scol;
  const unsigned short* pA1 = X + (long)ga1 * K + scol;
  unsigned short* lA0 = As + (wid << 5) * BK;
  unsigned short* lA1 = lA0 + 16 * BK;
  // B fp32 reg-staging: lane covers rows (tid>>3)+32j, cols (tid&7)*4..+4
  const int brow = tid >> 3, bcol = (tid & 7) << 2;
  const float* pB = W + (long)(bn * BN + brow) * K + bcol;
  unsigned short* lB = Bs + brow * BK + bcol;
  f32x4 acc[4][4];
  const f32x4 zero = {0.0f, 0.0f, 0.0f, 0.0f};
#pragma unroll
  for (int m = 0; m < 4; ++m)
#pragma unroll
    for (int n = 0; n < 4; ++n) acc[m][n] = zero;
  const int wm = (wid >> 1) << 6, wn = (wid & 1) << 6;
  for (int k0 = 0; k0 < K; k0 += BK) {
    __syncthreads();
    gload16(pA0 + k0, lA0);
    gload16(pA1 + k0, lA1);
#pragma unroll
    for (int j = 0; j < 4; ++j) {
      const float4 v = *(const float4*)(pB + (long)(j * 32) * K + k0);
      ushort4 o;
      o.x = f2bf(v.x); o.y = f2bf(v.y); o.z = f2bf(v.z); o.w = f2bf(v.w);
      *(ushort4*)(lB + j * 32 * BK) = o;
    }
    __syncthreads();
    bf16x8 av[4], bv[4];
#pragma unroll
    for (int m = 0; m < 4; ++m)
      av[m] = *(const bf16x8*)(As + (wm + m * 16 + lr) * BK + (lq << 3));
#pragma unroll
    for (int n = 0; n < 4; ++n)
      bv[n] = *(const bf16x8*)(Bs + (wn + n * 16 + lr) * BK + (lq << 3));
#pragma unroll
    for (int m = 0; m < 4; ++m)
#pragma unroll
      for (int n = 0; n < 4; ++n)
        acc[m][n] = __builtin_amdgcn_mfma_f32_16x16x32_bf16(av[m], bv[n], acc[m][n], 0, 0, 0);
  }
  const int row0 = bm * BM + wm, col0 = bn * BN + wn;
#pragma unroll
  for (int m = 0; m < 4; ++m) {
#pragma unroll
    for (int n = 0; n < 4; ++n) {
      const int cc = col0 + n * 16 + lr;
      const float bb = bias[cc];
#pragma unroll
      for (int e = 0; e < 4; ++e) {
        const int rr = row0 + m * 16 + (lq << 2) + e;
        float h = acc[m][n][e] + bb;
        h = 0.5f * h * (1.0f + erff(h * 0.70710678118654752f));  // exact gelu
        H[(long)rr * N + cc] = f2bf(h);
      }
    }
  }
}

// ---------------- GEMM2 (split-K): Pp[s] = H_chunk @ Wproj_chunk^T ----------------
__global__ __launch_bounds__(256) void gemm_proj_kernel(
    const unsigned short* __restrict__ Hin,
    const float* __restrict__ W,
    float* __restrict__ Pp,
    const int* __restrict__ cnt,
    const int rowbase, const int N, const int K, const int Kc, const long pstride) {
  __shared__ alignas(16) unsigned short As[BM * BK];
  __shared__ alignas(16) unsigned short Bs[BN * BK];
  const int M = *cnt;
  const int bn = blockIdx.x, bm = blockIdx.y, sz = blockIdx.z;
  if (rowbase + bm * BM >= M) return;
  const int tid = threadIdx.x, wid = tid >> 6, lane = tid & 63;
  const int lr = lane & 15, lq = lane >> 4;
  const int srow = (wid << 5) + (lane >> 2);
  const int scol = (lane & 3) << 3;
  const unsigned short* pA0 = Hin + (long)(bm * BM + srow) * K + scol;
  const unsigned short* pA1 = Hin + (long)(bm * BM + srow + 16) * K + scol;
  unsigned short* lA0 = As + (wid << 5) * BK;
  unsigned short* lA1 = lA0 + 16 * BK;
  const int brow = tid >> 3, bcol = (tid & 7) << 2;
  const float* pB = W + (long)(bn * BN + brow) * K + bcol;
  unsigned short* lB = Bs + brow * BK + bcol;
  f32x4 acc[4][4];
  const f32x4 zero = {0.0f, 0.0f, 0.0f, 0.0f};
#pragma unroll
  for (int m = 0; m < 4; ++m)
#pragma unroll
    for (int n = 0; n < 4; ++n) acc[m][n] = zero;
  const int wm = (wid >> 1) << 6, wn = (wid & 1) << 6;
  const int kbeg = sz * Kc, kend = kbeg + Kc;
  for (int k0 = kbeg; k0 < kend; k0 += BK) {
    __syncthreads();
    gload16(pA0 + k0, lA0);
    gload16(pA1 + k0, lA1);
#pragma unroll
    for (int j = 0; j < 4; ++j) {
      const float4 v = *(const float4*)(pB + (long)(j * 32) * K + k0);
      ushort4 o;
      o.x = f2bf(v.x); o.y = f2bf(v.y); o.z = f2bf(v.z); o.w = f2bf(v.w);
      *(ushort4*)(lB + j * 32 * BK) = o;
    }
    __syncthreads();
    bf16x8 av[4], bv[4];
#pragma unroll
    for (int m = 0; m < 4; ++m)
      av[m] = *(const bf16x8*)(As + (wm + m * 16 + lr) * BK + (lq << 3));
#pragma unroll
    for (int n = 0; n < 4; ++n)
      bv[n] = *(const bf16x8*)(Bs + (wn + n * 16 + lr) * BK + (lq << 3));
#pragma unroll
    for (int m = 0; m < 4; ++m)
#pragma unroll
      for (int n = 0; n < 4; ++n)
        acc[m][n] = __builtin_amdgcn_mfma_f32_16x16x32_bf16(av[m], bv[n], acc[m][n], 0, 0, 0);
  }
  float* Pout = Pp + (long)sz * pstride;
  const int row0 = bm * BM + wm, col0 = bn * BN + wn;
#pragma unroll
  for (int m = 0; m < 4; ++m)
#pragma unroll
    for (int n = 0; n < 4; ++n) {
      const int cc = col0 + n * 16 + lr;
#pragma unroll
      for (int e = 0; e < 4; ++e) {
        const int rr = row0 + m * 16 + (lq << 2) + e;
        Pout[(long)rr * N + cc] = acc[m][n][e];
      }
    }
}

// ---------------- reduce split-K partials + bias, scatter to out ----------------
__global__ __launch_bounds__(256) void reduce_kernel(
    const float* __restrict__ Pp, const float* __restrict__ bias,
    const int* __restrict__ idx, const int* __restrict__ cnt,
    float* __restrict__ out, const int D, const long pstride,
    const int rowbase, const int CH) {
  const int M = *cnt;
  int rows = M - rowbase;
  if (rows <= 0) return;
  if (rows > CH) rows = CH;
  const long total = (long)rows * D / 4;
  long i = blockIdx.x * 256L + threadIdx.x;
  const long stride = (long)gridDim.x * 256L;
  for (; i < total; i += stride) {
    const long e = i << 2;
    const int r = (int)(e / D);
    const int d = (int)(e - (long)r * D);
    const float4 a = *(const float4*)(Pp + e);
    const float4 b = *(const float4*)(Pp + pstride + e);
    const float4 c = *(const float4*)(Pp + 2 * pstride + e);
    const float4 f = *(const float4*)(Pp + 3 * pstride + e);
    const float4 bb = *(const float4*)(bias + d);
    float4 o;
    o.x = a.x + b.x + c.x + f.x + bb.x;
    o.y = a.y + b.y + c.y + f.y + bb.y;
    o.z = a.z + b.z + c.z + f.z + bb.z;
    o.w = a.w + b.w + c.w + f.w + bb.w;
    *(float4*)(out + (long)idx[rowbase + r] * D + d) = o;
  }
}

extern "C" void kernel_launch(void* const* d_in, const int* in_sizes, int n_in,
                              void* d_out, int out_size, void* d_ws, size_t ws_size,
                              hipStream_t stream) {
  const float* x   = (const float*)d_in[0];
  const void* mask = d_in[1];
  const float* wfs = (const float*)d_in[2];
  const float* bfs = (const float*)d_in[3];
  const float* wps = (const float*)d_in[4];
  const float* bps = (const float*)d_in[5];
  const float* wfb = (const float*)d_in[6];
  const float* bfb = (const float*)d_in[7];
  const float* wpb = (const float*)d_in[8];
  const float* bpb = (const float*)d_in[9];
  float* out = (float*)d_out;

  const int n_tok = in_sizes[1];            // 8192
  const int D  = in_sizes[0] / n_tok;       // 1024
  const int Fs = in_sizes[3];               // 4096
  const int Fb = in_sizes[7];               // 16384

  char* ws = (char*)d_ws;
  size_t off = 0;
  auto alloc = [&](size_t b) { void* p = ws + off; off += (b + 255) & ~(size_t)255; return p; };
  unsigned short* x_bf = (unsigned short*)alloc((size_t)n_tok * D * 2);
  int* idx_s  = (int*)alloc((size_t)n_tok * 4);
  int* idx_b  = (int*)alloc((size_t)n_tok * 4);
  int* counts = (int*)alloc(256);
  const size_t fixed = off;

  // Chunk size: largest CH whose H chunk (CH*Fb bf16) + split-K partials
  // (CH*D*4 fp32) fit the remaining workspace. Floor CH=256 (~28 MB total).
  int CH = 2048;
  while (CH > 256 &&
         fixed + (size_t)CH * Fb * 2 + (size_t)CH * D * 16 + 1024 > ws_size)
    CH >>= 1;
  unsigned short* Hbuf = (unsigned short*)alloc((size_t)CH * Fb * 2);
  float* Pp = (float*)alloc((size_t)CH * D * 16);
  const long pstride = (long)CH * D;
  const int NC = n_tok / CH;

  {
    int n4 = (int)(((size_t)n_tok * D) >> 2);
    int g = (n4 + 255) / 256; if (g > 2048) g = 2048;
    cvt_kernel<<<dim3(g), dim3(256), 0, stream>>>(x, x_bf, n4);
  }
  route_kernel<<<dim3(1), dim3(256), 0, stream>>>(mask, n_tok, idx_s, idx_b, counts);

  struct Ex { const float *wf, *bf, *wp, *bp; const int *cnt, *idx; int F; };
  const Ex ex[2] = {
      {wfs, bfs, wps, bps, counts + 0, idx_s, Fs},
      {wfb, bfb, wpb, bpb, counts + 1, idx_b, Fb},
  };
  for (int e = 0; e < 2; ++e) {
    const Ex& E = ex[e];
    for (int c = 0; c < NC; ++c) {
      const int rb = c * CH;
      gemm_fc_kernel<<<dim3(E.F / BN, CH / BM), dim3(256), 0, stream>>>(
          x_bf, E.wf, E.bf, Hbuf, E.idx, E.cnt, rb, E.F, D);
      gemm_proj_kernel<<<dim3(D / BN, CH / BM, 4), dim3(256), 0, stream>>>(
          Hbuf, E.wp, Pp, E.cnt, rb, D, E.F, E.F / 4, pstride);
      reduce_kernel<<<dim3(1024), dim3(256), 0, stream>>>(
          Pp, E.bp, E.idx, E.cnt, out, D, pstride, rb, CH);
    }
  }
}

// Round 3
// 931.714 us; speedup vs baseline: 1.1607x; 1.1607x over previous
//
#include <hip/hip_runtime.h>
#include <hip/hip_bf16.h>

typedef __attribute__((ext_vector_type(4))) float f32x4;
typedef __attribute__((ext_vector_type(8))) short bf16x8;

#define BM 128
#define BN 128
#define BK 32

__device__ __forceinline__ unsigned short f2bf(float f) {
  unsigned int u = __float_as_uint(f);
  u = (u + 0x7FFFu + ((u >> 16) & 1u)) >> 16;
  return (unsigned short)u;
}

__device__ __forceinline__ void gload16(const void* g, void* l) {
  __builtin_amdgcn_global_load_lds(
      (const __attribute__((address_space(1))) void*)g,
      (__attribute__((address_space(3))) void*)l,
      16, 0, 0);
}

// ---------------- fp32 -> bf16 convert (weights) ----------------
__global__ __launch_bounds__(256) void cvt_kernel(const float* __restrict__ in,
                                                  unsigned short* __restrict__ out,
                                                  int n4) {
  int i = blockIdx.x * 256 + threadIdx.x;
  const int stride = gridDim.x * 256;
  for (; i < n4; i += stride) {
    const float4 v = ((const float4*)in)[i];
    ushort4 o;
    o.x = f2bf(v.x); o.y = f2bf(v.y); o.z = f2bf(v.z); o.w = f2bf(v.w);
    ((ushort4*)out)[i] = o;
  }
}

// ---------------- routing: compact token indices per expert ----------------
__global__ __launch_bounds__(256) void route_kernel(const void* __restrict__ mask,
                                                    int n_tok,
                                                    int* __restrict__ idx_s,
                                                    int* __restrict__ idx_b,
                                                    int* __restrict__ counts) {
  __shared__ int mode_sh;
  __shared__ int cs[256], cb[256];
  __shared__ int os[256], ob[256];
  const unsigned char* mb = (const unsigned char*)mask;
  const int* mi = (const int*)mask;
  const int tid = threadIdx.x;
  if (tid == 0) mode_sh = 0;
  __syncthreads();
  int found = 0;
  for (int i = tid; i < n_tok; i += 256)
    if ((i & 3) == 1 && mb[i]) found = 1;   // int32/fp32 bools have byte1 == 0
  if (found) atomicOr(&mode_sh, 1);
  __syncthreads();
  const int byte_mode = mode_sh;
  const int per = n_tok / 256;
  const int t0 = tid * per;
  for (int i = 0; i < per; ++i) { idx_s[t0 + i] = 0; idx_b[t0 + i] = 0; }
  int ls = 0, lb = 0;
  for (int i = 0; i < per; ++i) {
    const int m = byte_mode ? (mb[t0 + i] != 0) : (mi[t0 + i] != 0);
    ls += !m; lb += m;
  }
  cs[tid] = ls; cb[tid] = lb;
  __syncthreads();
  if (tid == 0) {
    int as = 0, ab = 0;
    for (int i = 0; i < 256; ++i) { os[i] = as; ob[i] = ab; as += cs[i]; ab += cb[i]; }
    counts[0] = as; counts[1] = ab;
  }
  __syncthreads();
  int ps = os[tid], pb = ob[tid];
  for (int i = 0; i < per; ++i) {
    const int m = byte_mode ? (mb[t0 + i] != 0) : (mi[t0 + i] != 0);
    if (m) idx_b[pb++] = t0 + i; else idx_s[ps++] = t0 + i;
  }
}

// ---------------- gather + fp32->bf16: xg_e[r] = bf16(x[idx_e[r]]) ----------------
__global__ __launch_bounds__(256) void gather_cvt_kernel(
    const float* __restrict__ x,
    const int* __restrict__ idx_s, const int* __restrict__ idx_b,
    unsigned short* __restrict__ xg_s, unsigned short* __restrict__ xg_b,
    const int n_tok, const int D) {
  const int gpr = D >> 3;
  const int total = 2 * n_tok * gpr;
  int g = blockIdx.x * 256 + threadIdx.x;
  const int stride = gridDim.x * 256;
  for (; g < total; g += stride) {
    const int half = g >= n_tok * gpr;
    int gg = g - half * n_tok * gpr;
    const int r = gg / gpr;
    const int c = (gg - r * gpr) << 3;
    const int src = half ? idx_b[r] : idx_s[r];
    const float4 v0 = *(const float4*)(x + (long)src * D + c);
    const float4 v1 = *(const float4*)(x + (long)src * D + c + 4);
    ushort4 a, b;
    a.x = f2bf(v0.x); a.y = f2bf(v0.y); a.z = f2bf(v0.z); a.w = f2bf(v0.w);
    b.x = f2bf(v1.x); b.y = f2bf(v1.y); b.z = f2bf(v1.z); b.w = f2bf(v1.w);
    unsigned short* dst = (half ? xg_b : xg_s) + (long)r * D + c;
    *(ushort4*)dst = a;
    *(ushort4*)(dst + 4) = b;
  }
}

// ---------------- unified GEMM: C = A @ B^T (B torch [out,in] layout) ----------------
// A [*, K] bf16 rows arow0+tile; B [N,K] bf16 (BF16B) or fp32 (converted in staging).
// GELU=1: H[row][col] = bf16(gelu(acc + bias[col])).  GELU=0: Pp[z][row][col] = acc.
template <int BF16B, int GELU>
__global__ __launch_bounds__(256) void gemm_kernel(
    const unsigned short* __restrict__ A,
    const void* __restrict__ Bv,
    const float* __restrict__ bias,
    unsigned short* __restrict__ Hout,
    float* __restrict__ Pout,
    const int* __restrict__ cnt,
    const int rowbase, const int arow0,
    const int N, const int K, const int Kc, const long pstride) {
  __shared__ alignas(16) unsigned short As[BM * BK];
  __shared__ alignas(16) unsigned short Bs[BN * BK];
  const int M = *cnt;
  const int bn = blockIdx.x, bm = blockIdx.y, sz = blockIdx.z;
  if (rowbase + bm * BM >= M) return;
  const int tid = threadIdx.x, wid = tid >> 6, lane = tid & 63;
  const int lr = lane & 15, lq = lane >> 4;
  // A staging: global_load_lds, 16B/lane, linear dest
  const int srow = (wid << 5) + (lane >> 2);
  const int scol = (lane & 3) << 3;
  const unsigned short* pA0 = A + (long)(arow0 + bm * BM + srow) * K + scol;
  const unsigned short* pA1 = pA0 + (long)16 * K;
  unsigned short* lA0 = As + (wid << 5) * BK;
  unsigned short* lA1 = lA0 + 16 * BK;
  // B staging
  const unsigned short* pB0 = nullptr; const unsigned short* pB1 = nullptr;
  const float* pBf = nullptr;
  unsigned short* lB0 = Bs + (wid << 5) * BK;
  unsigned short* lB1 = lB0 + 16 * BK;
  unsigned short* lBf = nullptr;
  if constexpr (BF16B) {
    const unsigned short* B = (const unsigned short*)Bv;
    pB0 = B + (long)(bn * BN + srow) * K + scol;
    pB1 = pB0 + (long)16 * K;
  } else {
    const float* B = (const float*)Bv;
    const int brow = tid >> 3, bcol = (tid & 7) << 2;
    pBf = B + (long)(bn * BN + brow) * K + bcol;
    lBf = Bs + brow * BK + bcol;
  }
  f32x4 acc[4][4];
  const f32x4 zero = {0.0f, 0.0f, 0.0f, 0.0f};
#pragma unroll
  for (int m = 0; m < 4; ++m)
#pragma unroll
    for (int n = 0; n < 4; ++n) acc[m][n] = zero;
  const int wm = (wid >> 1) << 6, wn = (wid & 1) << 6;
  const int kbeg = sz * Kc, kend = kbeg + Kc;
  for (int k0 = kbeg; k0 < kend; k0 += BK) {
    __syncthreads();
    gload16(pA0 + k0, lA0);
    gload16(pA1 + k0, lA1);
    if constexpr (BF16B) {
      gload16(pB0 + k0, lB0);
      gload16(pB1 + k0, lB1);
    } else {
#pragma unroll
      for (int j = 0; j < 4; ++j) {
        const float4 v = *(const float4*)(pBf + (long)(j * 32) * K + k0);
        ushort4 o;
        o.x = f2bf(v.x); o.y = f2bf(v.y); o.z = f2bf(v.z); o.w = f2bf(v.w);
        *(ushort4*)(lBf + j * 32 * BK) = o;
      }
    }
    __syncthreads();
    bf16x8 av[4], bv[4];
#pragma unroll
    for (int m = 0; m < 4; ++m)
      av[m] = *(const bf16x8*)(As + (wm + m * 16 + lr) * BK + (lq << 3));
#pragma unroll
    for (int n = 0; n < 4; ++n)
      bv[n] = *(const bf16x8*)(Bs + (wn + n * 16 + lr) * BK + (lq << 3));
#pragma unroll
    for (int m = 0; m < 4; ++m)
#pragma unroll
      for (int n = 0; n < 4; ++n)
        acc[m][n] = __builtin_amdgcn_mfma_f32_16x16x32_bf16(av[m], bv[n], acc[m][n], 0, 0, 0);
  }
  const int row0 = bm * BM + wm, col0 = bn * BN + wn;
#pragma unroll
  for (int m = 0; m < 4; ++m) {
#pragma unroll
    for (int n = 0; n < 4; ++n) {
      const int cc = col0 + n * 16 + lr;
      float bb = 0.0f;
      if constexpr (GELU) bb = bias[cc];
#pragma unroll
      for (int e = 0; e < 4; ++e) {
        const int rr = row0 + m * 16 + (lq << 2) + e;
        if constexpr (GELU) {
          float h = acc[m][n][e] + bb;
          h = 0.5f * h * (1.0f + erff(h * 0.70710678118654752f));
          Hout[(long)rr * N + cc] = f2bf(h);
        } else {
          Pout[(long)sz * pstride + (long)rr * N + cc] = acc[m][n][e];
        }
      }
    }
  }
}

// ---------------- reduce split-K partials + bias, scatter to out ----------------
__global__ __launch_bounds__(256) void reduce_kernel(
    const float* __restrict__ Pp, const float* __restrict__ bias,
    const int* __restrict__ idx, const int* __restrict__ cnt,
    float* __restrict__ out, const int D, const long pstride,
    const int rowbase, const int CH, const int Z) {
  const int M = *cnt;
  int rows = M - rowbase;
  if (rows <= 0) return;
  if (rows > CH) rows = CH;
  const long total = (long)rows * (D >> 2);
  long i = blockIdx.x * 256L + threadIdx.x;
  const long stride = (long)gridDim.x * 256L;
  for (; i < total; i += stride) {
    const long e = i << 2;
    const int r = (int)(e / D);
    const int d = (int)(e - (long)r * D);
    float4 s = *(const float4*)(Pp + (long)r * D + d);
    for (int z = 1; z < Z; ++z) {
      const float4 p = *(const float4*)(Pp + (long)z * pstride + (long)r * D + d);
      s.x += p.x; s.y += p.y; s.z += p.z; s.w += p.w;
    }
    const float4 bb = *(const float4*)(bias + d);
    s.x += bb.x; s.y += bb.y; s.z += bb.z; s.w += bb.w;
    *(float4*)(out + (long)idx[rowbase + r] * D + d) = s;
  }
}

extern "C" void kernel_launch(void* const* d_in, const int* in_sizes, int n_in,
                              void* d_out, int out_size, void* d_ws, size_t ws_size,
                              hipStream_t stream) {
  const float* x   = (const float*)d_in[0];
  const void* mask = d_in[1];
  const float* wfs = (const float*)d_in[2];
  const float* bfs = (const float*)d_in[3];
  const float* wps = (const float*)d_in[4];
  const float* bps = (const float*)d_in[5];
  const float* wfb = (const float*)d_in[6];
  const float* bfb = (const float*)d_in[7];
  const float* wpb = (const float*)d_in[8];
  const float* bpb = (const float*)d_in[9];
  float* out = (float*)d_out;

  const int n_tok = in_sizes[1];            // 8192
  const int D  = in_sizes[0] / n_tok;       // 1024
  const int Fs = in_sizes[3];               // 4096
  const int Fb = in_sizes[7];               // 16384

  char* ws = (char*)d_ws;
  size_t off = 0;
  auto alloc = [&](size_t b) { void* p = ws + off; off += (b + 255) & ~(size_t)255; return p; };

  // fixed allocations
  int* idx_s  = (int*)alloc((size_t)n_tok * 4);
  int* idx_b  = (int*)alloc((size_t)n_tok * 4);
  int* counts = (int*)alloc(256);
  unsigned short* xg_s = (unsigned short*)alloc((size_t)n_tok * D * 2);
  unsigned short* xg_b = (unsigned short*)alloc((size_t)n_tok * D * 2);
  const size_t fixed = off;

  // tier search: prefer full weight preconversion + large chunks; never exceed ws_size
  struct Tier { int preS, preB, CH, Z; };
  const Tier tiers[] = {
      {1, 1, 2048, 4}, {1, 1, 1024, 8}, {0, 1, 1024, 8}, {0, 1, 512, 8},
      {0, 0, 1024, 8}, {0, 0, 512, 8}, {0, 0, 256, 8}};
  int preS = 0, preB = 0, CH = 256, Z = 8;
  for (const Tier& t : tiers) {
    const size_t need = fixed +
        (t.preS ? 2 * (size_t)Fs * D * 2 + 512 : 0) +
        (t.preB ? 2 * (size_t)Fb * D * 2 + 512 : 0) +
        (size_t)t.CH * Fb * 2 + (size_t)t.Z * t.CH * D * 4 + 4096;
    if (need <= ws_size) { preS = t.preS; preB = t.preB; CH = t.CH; Z = t.Z; break; }
  }
  unsigned short* wfs_bf = preS ? (unsigned short*)alloc((size_t)Fs * D * 2) : nullptr;
  unsigned short* wps_bf = preS ? (unsigned short*)alloc((size_t)Fs * D * 2) : nullptr;
  unsigned short* wfb_bf = preB ? (unsigned short*)alloc((size_t)Fb * D * 2) : nullptr;
  unsigned short* wpb_bf = preB ? (unsigned short*)alloc((size_t)Fb * D * 2) : nullptr;
  unsigned short* Hbuf = (unsigned short*)alloc((size_t)CH * Fb * 2);
  float* Pp = (float*)alloc((size_t)Z * CH * D * 4);
  const long pstride = (long)CH * D;
  const int NC = n_tok / CH;

  route_kernel<<<dim3(1), dim3(256), 0, stream>>>(mask, n_tok, idx_s, idx_b, counts);
  gather_cvt_kernel<<<dim3(4096), dim3(256), 0, stream>>>(
      x, idx_s, idx_b, xg_s, xg_b, n_tok, D);
  auto cvtl = [&](const float* src, unsigned short* dst, size_t n) {
    int n4 = (int)(n >> 2);
    int g = (n4 + 255) / 256; if (g > 2048) g = 2048;
    cvt_kernel<<<dim3(g), dim3(256), 0, stream>>>(src, dst, n4);
  };
  if (preS) { cvtl(wfs, wfs_bf, (size_t)Fs * D); cvtl(wps, wps_bf, (size_t)Fs * D); }
  if (preB) { cvtl(wfb, wfb_bf, (size_t)Fb * D); cvtl(wpb, wpb_bf, (size_t)Fb * D); }

  struct Ex {
    const unsigned short* xg; const int *idx, *cnt;
    const void *wf, *wp; const float *bf, *bp; int F, pre;
  };
  const Ex ex[2] = {
      {xg_s, idx_s, counts + 0,
       preS ? (const void*)wfs_bf : (const void*)wfs,
       preS ? (const void*)wps_bf : (const void*)wps, bfs, bps, Fs, preS},
      {xg_b, idx_b, counts + 1,
       preB ? (const void*)wfb_bf : (const void*)wfb,
       preB ? (const void*)wpb_bf : (const void*)wpb, bfb, bpb, Fb, preB},
  };
  for (int e = 0; e < 2; ++e) {
    const Ex& E = ex[e];
    const int Kc = E.F / Z;
    for (int c = 0; c < NC; ++c) {
      const int rb = c * CH;
      const dim3 gfc(E.F / BN, CH / BM, 1);
      const dim3 gpr(D / BN, CH / BM, Z);
      if (E.pre) {
        gemm_kernel<1, 1><<<gfc, dim3(256), 0, stream>>>(
            E.xg, E.wf, E.bf, Hbuf, nullptr, E.cnt, rb, rb, E.F, D, D, 0);
        gemm_kernel<1, 0><<<gpr, dim3(256), 0, stream>>>(
            Hbuf, E.wp, nullptr, nullptr, Pp, E.cnt, rb, 0, D, E.F, Kc, pstride);
      } else {
        gemm_kernel<0, 1><<<gfc, dim3(256), 0, stream>>>(
            E.xg, E.wf, E.bf, Hbuf, nullptr, E.cnt, rb, rb, E.F, D, D, 0);
        gemm_kernel<0, 0><<<gpr, dim3(256), 0, stream>>>(
            Hbuf, E.wp, nullptr, nullptr, Pp, E.cnt, rb, 0, D, E.F, Kc, pstride);
      }
      reduce_kernel<<<dim3(1024), dim3(256), 0, stream>>>(
          Pp, E.bp, E.idx, E.cnt, out, D, pstride, rb, CH, Z);
    }
  }
}

// Round 5
// 891.824 us; speedup vs baseline: 1.2126x; 1.0447x over previous
//
#include <hip/hip_runtime.h>
#include <hip/hip_bf16.h>

typedef __attribute__((ext_vector_type(4))) float f32x4;
typedef __attribute__((ext_vector_type(8))) short bf16x8;

#define BM 128
#define BN 128
#define BK 32

__device__ __forceinline__ unsigned short f2bf(float f) {
  unsigned int u = __float_as_uint(f);
  u = (u + 0x7FFFu + ((u >> 16) & 1u)) >> 16;
  return (unsigned short)u;
}

// tanh-form gelu: 0.5h(1+tanh(sqrt(2/pi)(h+0.044715h^3))) = h*sigmoid(-q), ~8 VALU ops.
// |gelu_tanh - gelu_erf| < 3.2e-4 absolute — far under tolerance.
__device__ __forceinline__ float gelu_f(float h) {
  const float k0 = -1.5957691216057308f;     // -2*sqrt(2/pi)
  const float k1 = -0.07135481627333355f;    // -2*sqrt(2/pi)*0.044715
  const float h2 = h * h;
  const float q = h * fmaf(k1, h2, k0);      // -2*u
  const float e = __expf(q);
  return h * __fdividef(1.0f, 1.0f + e);
}

__device__ __forceinline__ void gload16(const void* g, void* l) {
  __builtin_amdgcn_global_load_lds(
      (const __attribute__((address_space(1))) void*)g,
      (__attribute__((address_space(3))) void*)l,
      16, 0, 0);
}

// bijective XCD-aware swizzle (m204): contiguous new-id chunk per XCD
__device__ __forceinline__ void xcd_swz(int& bn, int& bm) {
  const int nx = gridDim.x, nwg = gridDim.x * gridDim.y;
  const int wg = blockIdx.x + nx * blockIdx.y;
  const int q = nwg >> 3, r = nwg & 7;
  const int xcd = wg & 7, pos = wg >> 3;
  const int base = xcd < r ? xcd * (q + 1) : r * (q + 1) + (xcd - r) * q;
  const int nid = base + pos;
  bn = nid % nx;
  bm = nid / nx;
}

// ---------------- fp32 -> bf16 convert (weights) ----------------
__global__ __launch_bounds__(256) void cvt_kernel(const float* __restrict__ in,
                                                  unsigned short* __restrict__ out,
                                                  int n4) {
  int i = blockIdx.x * 256 + threadIdx.x;
  const int stride = gridDim.x * 256;
  for (; i < n4; i += stride) {
    const float4 v = ((const float4*)in)[i];
    ushort4 o;
    o.x = f2bf(v.x); o.y = f2bf(v.y); o.z = f2bf(v.z); o.w = f2bf(v.w);
    ((ushort4*)out)[i] = o;
  }
}

// ---------------- routing: compact token indices per expert ----------------
__global__ __launch_bounds__(256) void route_kernel(const void* __restrict__ mask,
                                                    int n_tok,
                                                    int* __restrict__ idx_s,
                                                    int* __restrict__ idx_b,
                                                    int* __restrict__ counts) {
  __shared__ int mode_sh;
  __shared__ int cs[256], cb[256];
  __shared__ int os[256], ob[256];
  const unsigned char* mb = (const unsigned char*)mask;
  const int* mi = (const int*)mask;
  const int tid = threadIdx.x;
  if (tid == 0) mode_sh = 0;
  __syncthreads();
  int found = 0;
  for (int i = tid; i < n_tok; i += 256)
    if ((i & 3) == 1 && mb[i]) found = 1;   // int32/fp32 bools have byte1 == 0
  if (found) atomicOr(&mode_sh, 1);
  __syncthreads();
  const int byte_mode = mode_sh;
  const int per = n_tok / 256;
  const int t0 = tid * per;
  for (int i = 0; i < per; ++i) { idx_s[t0 + i] = 0; idx_b[t0 + i] = 0; }
  int ls = 0, lb = 0;
  for (int i = 0; i < per; ++i) {
    const int m = byte_mode ? (mb[t0 + i] != 0) : (mi[t0 + i] != 0);
    ls += !m; lb += m;
  }
  cs[tid] = ls; cb[tid] = lb;
  __syncthreads();
  if (tid == 0) {
    int as = 0, ab = 0;
    for (int i = 0; i < 256; ++i) { os[i] = as; ob[i] = ab; as += cs[i]; ab += cb[i]; }
    counts[0] = as; counts[1] = ab;
  }
  __syncthreads();
  int ps = os[tid], pb = ob[tid];
  for (int i = 0; i < per; ++i) {
    const int m = byte_mode ? (mb[t0 + i] != 0) : (mi[t0 + i] != 0);
    if (m) idx_b[pb++] = t0 + i; else idx_s[ps++] = t0 + i;
  }
}

// ---------------- gather + fp32->bf16: xg_e[r] = bf16(x[idx_e[r]]) ----------------
__global__ __launch_bounds__(256) void gather_cvt_kernel(
    const float* __restrict__ x,
    const int* __restrict__ idx_s, const int* __restrict__ idx_b,
    unsigned short* __restrict__ xg_s, unsigned short* __restrict__ xg_b,
    const int n_tok, const int D) {
  const int gpr = D >> 3;
  const int total = 2 * n_tok * gpr;
  int g = blockIdx.x * 256 + threadIdx.x;
  const int stride = gridDim.x * 256;
  for (; g < total; g += stride) {
    const int half = g >= n_tok * gpr;
    int gg = g - half * n_tok * gpr;
    const int r = gg / gpr;
    const int c = (gg - r * gpr) << 3;
    const int src = half ? idx_b[r] : idx_s[r];
    const float4 v0 = *(const float4*)(x + (long)src * D + c);
    const float4 v1 = *(const float4*)(x + (long)src * D + c + 4);
    ushort4 a, b;
    a.x = f2bf(v0.x); a.y = f2bf(v0.y); a.z = f2bf(v0.z); a.w = f2bf(v0.w);
    b.x = f2bf(v1.x); b.y = f2bf(v1.y); b.z = f2bf(v1.z); b.w = f2bf(v1.w);
    unsigned short* dst = (half ? xg_b : xg_s) + (long)r * D + c;
    *(ushort4*)dst = a;
    *(ushort4*)(dst + 4) = b;
  }
}

// ---------------- unified GEMM: C = A @ B^T (B torch [out,in] layout) ----------------
// GELU=1: H[row][col] = bf16(gelu(acc + bias[col])).  GELU=0: Pp[z][row][col] = acc.
template <int BF16B, int GELU>
__global__ __launch_bounds__(256) void gemm_kernel(
    const unsigned short* __restrict__ A,
    const void* __restrict__ Bv,
    const float* __restrict__ bias,
    unsigned short* __restrict__ Hout,
    float* __restrict__ Pout,
    const int* __restrict__ cnt,
    const int rowbase, const int arow0,
    const int N, const int K, const int Kc, const long pstride) {
  __shared__ alignas(16) unsigned short As[BM * BK];
  __shared__ alignas(16) unsigned short Bs[BN * BK];
  const int M = *cnt;
  int bn, bm;
  xcd_swz(bn, bm);
  const int sz = blockIdx.z;
  if (rowbase + bm * BM >= M) return;
  const int tid = threadIdx.x, wid = tid >> 6, lane = tid & 63;
  const int lr = lane & 15, lq = lane >> 4;
  // A staging: global_load_lds, 16B/lane, linear dest
  const int srow = (wid << 5) + (lane >> 2);
  const int scol = (lane & 3) << 3;
  const unsigned short* pA0 = A + (long)(arow0 + bm * BM + srow) * K + scol;
  const unsigned short* pA1 = pA0 + (long)16 * K;
  unsigned short* lA0 = As + (wid << 5) * BK;
  unsigned short* lA1 = lA0 + 16 * BK;
  // B staging
  const unsigned short* pB0 = nullptr; const unsigned short* pB1 = nullptr;
  const float* pBf = nullptr;
  unsigned short* lB0 = Bs + (wid << 5) * BK;
  unsigned short* lB1 = lB0 + 16 * BK;
  unsigned short* lBf = nullptr;
  if constexpr (BF16B) {
    const unsigned short* B = (const unsigned short*)Bv;
    pB0 = B + (long)(bn * BN + srow) * K + scol;
    pB1 = pB0 + (long)16 * K;
  } else {
    const float* B = (const float*)Bv;
    const int brow = tid >> 3, bcol = (tid & 7) << 2;
    pBf = B + (long)(bn * BN + brow) * K + bcol;
    lBf = Bs + brow * BK + bcol;
  }
  f32x4 acc[4][4];
  const f32x4 zero = {0.0f, 0.0f, 0.0f, 0.0f};
#pragma unroll
  for (int m = 0; m < 4; ++m)
#pragma unroll
    for (int n = 0; n < 4; ++n) acc[m][n] = zero;
  const int wm = (wid >> 1) << 6, wn = (wid & 1) << 6;
  const int kbeg = sz * Kc, kend = kbeg + Kc;
  for (int k0 = kbeg; k0 < kend; k0 += BK) {
    __syncthreads();
    gload16(pA0 + k0, lA0);
    gload16(pA1 + k0, lA1);
    if constexpr (BF16B) {
      gload16(pB0 + k0, lB0);
      gload16(pB1 + k0, lB1);
    } else {
#pragma unroll
      for (int j = 0; j < 4; ++j) {
        const float4 v = *(const float4*)(pBf + (long)(j * 32) * K + k0);
        ushort4 o;
        o.x = f2bf(v.x); o.y = f2bf(v.y); o.z = f2bf(v.z); o.w = f2bf(v.w);
        *(ushort4*)(lBf + j * 32 * BK) = o;
      }
    }
    __syncthreads();
    bf16x8 av[4], bv[4];
#pragma unroll
    for (int m = 0; m < 4; ++m)
      av[m] = *(const bf16x8*)(As + (wm + m * 16 + lr) * BK + (lq << 3));
#pragma unroll
    for (int n = 0; n < 4; ++n)
      bv[n] = *(const bf16x8*)(Bs + (wn + n * 16 + lr) * BK + (lq << 3));
#pragma unroll
    for (int m = 0; m < 4; ++m)
#pragma unroll
      for (int n = 0; n < 4; ++n)
        acc[m][n] = __builtin_amdgcn_mfma_f32_16x16x32_bf16(av[m], bv[n], acc[m][n], 0, 0, 0);
  }
  const int row0 = bm * BM + wm, col0 = bn * BN + wn;
#pragma unroll
  for (int m = 0; m < 4; ++m) {
#pragma unroll
    for (int n = 0; n < 4; ++n) {
      const int cc = col0 + n * 16 + lr;
      float bb = 0.0f;
      if constexpr (GELU) bb = bias[cc];
#pragma unroll
      for (int e = 0; e < 4; ++e) {
        const int rr = row0 + m * 16 + (lq << 2) + e;
        if constexpr (GELU) {
          Hout[(long)rr * N + cc] = f2bf(gelu_f(acc[m][n][e] + bb));
        } else {
          Pout[(long)sz * pstride + (long)rr * N + cc] = acc[m][n][e];
        }
      }
    }
  }
}

// ---------------- reduce split-K partials + bias, scatter to out ----------------
__global__ __launch_bounds__(256) void reduce_kernel(
    const float* __restrict__ Pp, const float* __restrict__ bias,
    const int* __restrict__ idx, const int* __restrict__ cnt,
    float* __restrict__ out, const int D, const long pstride,
    const int rowbase, const int CH, const int Z) {
  const int M = *cnt;
  int rows = M - rowbase;
  if (rows <= 0) return;
  if (rows > CH) rows = CH;
  const long total = (long)rows * (D >> 2);
  long i = blockIdx.x * 256L + threadIdx.x;
  const long stride = (long)gridDim.x * 256L;
  for (; i < total; i += stride) {
    const long e = i << 2;
    const int r = (int)(e / D);
    const int d = (int)(e - (long)r * D);
    float4 s = *(const float4*)(Pp + (long)r * D + d);
    for (int z = 1; z < Z; ++z) {
      const float4 p = *(const float4*)(Pp + (long)z * pstride + (long)r * D + d);
      s.x += p.x; s.y += p.y; s.z += p.z; s.w += p.w;
    }
    const float4 bb = *(const float4*)(bias + d);
    s.x += bb.x; s.y += bb.y; s.z += bb.z; s.w += bb.w;
    *(float4*)(out + (long)idx[rowbase + r] * D + d) = s;
  }
}

extern "C" void kernel_launch(void* const* d_in, const int* in_sizes, int n_in,
                              void* d_out, int out_size, void* d_ws, size_t ws_size,
                              hipStream_t stream) {
  const float* x   = (const float*)d_in[0];
  const void* mask = d_in[1];
  const float* wfs = (const float*)d_in[2];
  const float* bfs = (const float*)d_in[3];
  const float* wps = (const float*)d_in[4];
  const float* bps = (const float*)d_in[5];
  const float* wfb = (const float*)d_in[6];
  const float* bfb = (const float*)d_in[7];
  const float* wpb = (const float*)d_in[8];
  const float* bpb = (const float*)d_in[9];
  float* out = (float*)d_out;

  const int n_tok = in_sizes[1];            // 8192
  const int D  = in_sizes[0] / n_tok;       // 1024
  const int Fs = in_sizes[3];               // 4096
  const int Fb = in_sizes[7];               // 16384

  char* ws = (char*)d_ws;
  size_t off = 0;
  auto alloc = [&](size_t b) { void* p = ws + off; off += (b + 255) & ~(size_t)255; return p; };

  // fixed allocations
  int* idx_s  = (int*)alloc((size_t)n_tok * 4);
  int* idx_b  = (int*)alloc((size_t)n_tok * 4);
  int* counts = (int*)alloc(256);
  unsigned short* xg_s = (unsigned short*)alloc((size_t)n_tok * D * 2);
  unsigned short* xg_b = (unsigned short*)alloc((size_t)n_tok * D * 2);
  const size_t fixed = off;

  // tier search: prefer full weight preconversion + one big chunk; never exceed ws_size
  struct Tier { int preS, preB, CH, Z; };
  const Tier tiers[] = {
      {1, 1, 4096, 4}, {1, 1, 2048, 4}, {1, 1, 1024, 8}, {0, 1, 1024, 8},
      {0, 1, 512, 8}, {0, 0, 512, 8}, {0, 0, 256, 8}};
  int preS = 0, preB = 0, CH = 256, Z = 8;
  for (const Tier& t : tiers) {
    const size_t need = fixed +
        (t.preS ? 2 * (size_t)Fs * D * 2 + 512 : 0) +
        (t.preB ? 2 * (size_t)Fb * D * 2 + 512 : 0) +
        (size_t)t.CH * Fb * 2 + (size_t)t.Z * t.CH * D * 4 + 4096;
    if (need <= ws_size) { preS = t.preS; preB = t.preB; CH = t.CH; Z = t.Z; break; }
  }
  unsigned short* wfs_bf = preS ? (unsigned short*)alloc((size_t)Fs * D * 2) : nullptr;
  unsigned short* wps_bf = preS ? (unsigned short*)alloc((size_t)Fs * D * 2) : nullptr;
  unsigned short* wfb_bf = preB ? (unsigned short*)alloc((size_t)Fb * D * 2) : nullptr;
  unsigned short* wpb_bf = preB ? (unsigned short*)alloc((size_t)Fb * D * 2) : nullptr;
  unsigned short* Hbuf = (unsigned short*)alloc((size_t)CH * Fb * 2);
  float* Pp = (float*)alloc((size_t)Z * CH * D * 4);
  const long pstride = (long)CH * D;
  const int NC = n_tok / CH;

  route_kernel<<<dim3(1), dim3(256), 0, stream>>>(mask, n_tok, idx_s, idx_b, counts);
  gather_cvt_kernel<<<dim3(2048), dim3(256), 0, stream>>>(
      x, idx_s, idx_b, xg_s, xg_b, n_tok, D);
  auto cvtl = [&](const float* src, unsigned short* dst, size_t n) {
    int n4 = (int)(n >> 2);
    int g = (n4 + 255) / 256; if (g > 2048) g = 2048;
    cvt_kernel<<<dim3(g), dim3(256), 0, stream>>>(src, dst, n4);
  };
  if (preS) { cvtl(wfs, wfs_bf, (size_t)Fs * D); cvtl(wps, wps_bf, (size_t)Fs * D); }
  if (preB) { cvtl(wfb, wfb_bf, (size_t)Fb * D); cvtl(wpb, wpb_bf, (size_t)Fb * D); }

  struct Ex {
    const unsigned short* xg; const int *idx, *cnt;
    const void *wf, *wp; const float *bf, *bp; int F, pre;
  };
  const Ex ex[2] = {
      {xg_s, idx_s, counts + 0,
       preS ? (const void*)wfs_bf : (const void*)wfs,
       preS ? (const void*)wps_bf : (const void*)wps, bfs, bps, Fs, preS},
      {xg_b, idx_b, counts + 1,
       preB ? (const void*)wfb_bf : (const void*)wfb,
       preB ? (const void*)wpb_bf : (const void*)wpb, bfb, bpb, Fb, preB},
  };
  for (int e = 0; e < 2; ++e) {
    const Ex& E = ex[e];
    const int Kc = E.F / Z;
    for (int c = 0; c < NC; ++c) {
      const int rb = c * CH;
      const dim3 gfc(E.F / BN, CH / BM, 1);
      const dim3 gpr(D / BN, CH / BM, Z);
      if (E.pre) {
        gemm_kernel<1, 1><<<gfc, dim3(256), 0, stream>>>(
            E.xg, E.wf, E.bf, Hbuf, nullptr, E.cnt, rb, rb, E.F, D, D, 0);
        gemm_kernel<1, 0><<<gpr, dim3(256), 0, stream>>>(
            Hbuf, E.wp, nullptr, nullptr, Pp, E.cnt, rb, 0, D, E.F, Kc, pstride);
      } else {
        gemm_kernel<0, 1><<<gfc, dim3(256), 0, stream>>>(
            E.xg, E.wf, E.bf, Hbuf, nullptr, E.cnt, rb, rb, E.F, D, D, 0);
        gemm_kernel<0, 0><<<gpr, dim3(256), 0, stream>>>(
            Hbuf, E.wp, nullptr, nullptr, Pp, E.cnt, rb, 0, D, E.F, Kc, pstride);
      }
      reduce_kernel<<<dim3(1024), dim3(256), 0, stream>>>(
          Pp, E.bp, E.idx, E.cnt, out, D, pstride, rb, CH, Z);
    }
  }
}

// Round 6
// 795.050 us; speedup vs baseline: 1.3602x; 1.1217x over previous
//
#include <hip/hip_runtime.h>
#include <hip/hip_bf16.h>

typedef __attribute__((ext_vector_type(4))) float f32x4;
typedef __attribute__((ext_vector_type(8))) short bf16x8;

#define BM 128
#define BN 128
#define BK 32
#define CAP 4608            // token capacity per expert (+11 sigma over 4096)
#define GBM (CAP / BM)      // 36

__device__ __forceinline__ unsigned short f2bf(float f) {
  unsigned int u = __float_as_uint(f);
  u = (u + 0x7FFFu + ((u >> 16) & 1u)) >> 16;
  return (unsigned short)u;
}

// tanh-form gelu; |gelu_tanh - gelu_erf| < 3.2e-4 absolute — far under tolerance.
__device__ __forceinline__ float gelu_f(float h) {
  const float k0 = -1.5957691216057308f;
  const float k1 = -0.07135481627333355f;
  const float h2 = h * h;
  const float q = h * fmaf(k1, h2, k0);
  const float e = __expf(q);
  return h * __fdividef(1.0f, 1.0f + e);
}

__device__ __forceinline__ void gload16(const void* g, void* l) {
  __builtin_amdgcn_global_load_lds(
      (const __attribute__((address_space(1))) void*)g,
      (__attribute__((address_space(3))) void*)l,
      16, 0, 0);
}

// bijective XCD-aware swizzle (m204): per-XCD contiguous id chunk, bn-fastest
__device__ __forceinline__ void xcd_swz(int& bn, int& bm) {
  const int nx = gridDim.x, nwg = gridDim.x * gridDim.y;
  const int wg = blockIdx.x + nx * blockIdx.y;
  const int q = nwg >> 3, r = nwg & 7;
  const int xcd = wg & 7, pos = wg >> 3;
  const int base = xcd < r ? xcd * (q + 1) : r * (q + 1) + (xcd - r) * q;
  const int nid = base + pos;
  bn = nid % nx;
  bm = nid / nx;
}

// ---------------- fp32 -> bf16 convert (weights) ----------------
__global__ __launch_bounds__(256) void cvt_kernel(const float* __restrict__ in,
                                                  unsigned short* __restrict__ out,
                                                  int n4) {
  int i = blockIdx.x * 256 + threadIdx.x;
  const int stride = gridDim.x * 256;
  for (; i < n4; i += stride) {
    const float4 v = ((const float4*)in)[i];
    ushort4 o;
    o.x = f2bf(v.x); o.y = f2bf(v.y); o.z = f2bf(v.z); o.w = f2bf(v.w);
    ((ushort4*)out)[i] = o;
  }
}

// ---------------- routing: compact token indices per expert ----------------
__global__ __launch_bounds__(256) void route_kernel(const void* __restrict__ mask,
                                                    int n_tok,
                                                    int* __restrict__ idx_s,
                                                    int* __restrict__ idx_b,
                                                    int* __restrict__ counts) {
  __shared__ int mode_sh;
  __shared__ int cs[256], cb[256];
  __shared__ int os[256], ob[256];
  const unsigned char* mb = (const unsigned char*)mask;
  const int* mi = (const int*)mask;
  const int tid = threadIdx.x;
  if (tid == 0) mode_sh = 0;
  __syncthreads();
  int found = 0;
  for (int i = tid; i < n_tok; i += 256)
    if ((i & 3) == 1 && mb[i]) found = 1;   // int32/fp32 bools have byte1 == 0
  if (found) atomicOr(&mode_sh, 1);
  __syncthreads();
  const int byte_mode = mode_sh;
  const int per = n_tok / 256;
  const int t0 = tid * per;
  for (int i = 0; i < per; ++i) { idx_s[t0 + i] = 0; idx_b[t0 + i] = 0; }
  int ls = 0, lb = 0;
  for (int i = 0; i < per; ++i) {
    const int m = byte_mode ? (mb[t0 + i] != 0) : (mi[t0 + i] != 0);
    ls += !m; lb += m;
  }
  cs[tid] = ls; cb[tid] = lb;
  __syncthreads();
  if (tid == 0) {
    int as = 0, ab = 0;
    for (int i = 0; i < 256; ++i) { os[i] = as; ob[i] = ab; as += cs[i]; ab += cb[i]; }
    counts[0] = as; counts[1] = ab;
  }
  __syncthreads();
  int ps = os[tid], pb = ob[tid];
  for (int i = 0; i < per; ++i) {
    const int m = byte_mode ? (mb[t0 + i] != 0) : (mi[t0 + i] != 0);
    if (m) idx_b[pb++] = t0 + i; else idx_s[ps++] = t0 + i;
  }
}

// ---------------- combined gather + cvt: xg[0:ns)=small tokens, xg[ns:8192)=big ----------------
__global__ __launch_bounds__(256) void gather_cvt_kernel(
    const float* __restrict__ x,
    const int* __restrict__ idx_s, const int* __restrict__ idx_b,
    const int* __restrict__ counts,
    unsigned short* __restrict__ xg,
    const int n_tok, const int D) {
  const int gpr = D >> 3;
  const int total = n_tok * gpr;
  const int c0 = counts[0];
  int g = blockIdx.x * 256 + threadIdx.x;
  const int stride = gridDim.x * 256;
  for (; g < total; g += stride) {
    const int r = g / gpr;
    const int c = (g - r * gpr) << 3;
    const int src = r < c0 ? idx_s[r] : idx_b[r - c0];
    const float4 v0 = *(const float4*)(x + (long)src * D + c);
    const float4 v1 = *(const float4*)(x + (long)src * D + c + 4);
    ushort4 a, b;
    a.x = f2bf(v0.x); a.y = f2bf(v0.y); a.z = f2bf(v0.z); a.w = f2bf(v0.w);
    b.x = f2bf(v1.x); b.y = f2bf(v1.y); b.z = f2bf(v1.z); b.w = f2bf(v1.w);
    unsigned short* dst = xg + (long)r * D + c;
    *(ushort4*)dst = a;
    *(ushort4*)(dst + 4) = b;
  }
}

// ---------------- unified GEMM: C = A @ B^T ----------------
// MODE 0: H[r][c] = bf16(gelu(acc + bias[c]))   (fc slab; grid.z=1)
// MODE 1: Pp[z][r][c] = acc                      (proj slab 0; grid.z=2)
// MODE 2: Pp[z][r][c] += acc                     (proj slabs >0, C-in accumulate)
template <int BF16B, int MODE>
__global__ __launch_bounds__(256) void gemm_kernel(
    const unsigned short* __restrict__ A,
    const void* __restrict__ Bv,
    const float* __restrict__ bias,
    unsigned short* __restrict__ Hout,
    float* __restrict__ Pp,
    const int* __restrict__ counts, const int eidx, const int useAbase,
    const int N, const int astride, const int bstride,
    const int Kc, const long pstride) {
  __shared__ alignas(16) unsigned short As[BM * BK];
  __shared__ alignas(16) unsigned short Bs[BN * BK];
  const int M = counts[eidx];
  int bn, bm;
  xcd_swz(bn, bm);
  const int z = blockIdx.z;
  if (bm * BM >= M) return;
  const int abase = useAbase ? counts[0] : 0;
  const int tid = threadIdx.x, wid = tid >> 6, lane = tid & 63;
  const int lr = lane & 15, lq = lane >> 4;
  const int wm = (wid >> 1) << 6, wn = (wid & 1) << 6;
  const int row0 = bm * BM + wm, col0 = bn * BN + wn;
  // A staging: global_load_lds, 16B/lane, linear dest
  const int srow = (wid << 5) + (lane >> 2);
  const int scol = (lane & 3) << 3;
  const unsigned short* pA0 = A + (long)(abase + bm * BM + srow) * astride + scol;
  const unsigned short* pA1 = pA0 + (long)16 * astride;
  unsigned short* lA0 = As + (wid << 5) * BK;
  unsigned short* lA1 = lA0 + 16 * BK;
  // B staging
  const unsigned short* pB0 = nullptr; const unsigned short* pB1 = nullptr;
  const float* pBf = nullptr;
  unsigned short* lB0 = Bs + (wid << 5) * BK;
  unsigned short* lB1 = lB0 + 16 * BK;
  unsigned short* lBf = nullptr;
  if constexpr (BF16B) {
    const unsigned short* B = (const unsigned short*)Bv;
    pB0 = B + (long)(bn * BN + srow) * bstride + scol;
    pB1 = pB0 + (long)16 * bstride;
  } else {
    const float* B = (const float*)Bv;
    const int brow = tid >> 3, bcol = (tid & 7) << 2;
    pBf = B + (long)(bn * BN + brow) * bstride + bcol;
    lBf = Bs + brow * BK + bcol;
  }
  f32x4 acc[4][4];
  if constexpr (MODE == 2) {
#pragma unroll
    for (int m = 0; m < 4; ++m)
#pragma unroll
      for (int n = 0; n < 4; ++n) {
        const int cc = col0 + n * 16 + lr;
#pragma unroll
        for (int e = 0; e < 4; ++e) {
          const int rr = row0 + m * 16 + (lq << 2) + e;
          acc[m][n][e] = Pp[(long)z * pstride + (long)rr * N + cc];
        }
      }
  } else {
    const f32x4 zero = {0.0f, 0.0f, 0.0f, 0.0f};
#pragma unroll
    for (int m = 0; m < 4; ++m)
#pragma unroll
      for (int n = 0; n < 4; ++n) acc[m][n] = zero;
  }
  const int kbeg = z * Kc, kend = kbeg + Kc;
  for (int k0 = kbeg; k0 < kend; k0 += BK) {
    __syncthreads();
    gload16(pA0 + k0, lA0);
    gload16(pA1 + k0, lA1);
    if constexpr (BF16B) {
      gload16(pB0 + k0, lB0);
      gload16(pB1 + k0, lB1);
    } else {
#pragma unroll
      for (int j = 0; j < 4; ++j) {
        const float4 v = *(const float4*)(pBf + (long)(j * 32) * bstride + k0);
        ushort4 o;
        o.x = f2bf(v.x); o.y = f2bf(v.y); o.z = f2bf(v.z); o.w = f2bf(v.w);
        *(ushort4*)(lBf + j * 32 * BK) = o;
      }
    }
    __syncthreads();
    bf16x8 av[4], bv[4];
#pragma unroll
    for (int m = 0; m < 4; ++m)
      av[m] = *(const bf16x8*)(As + (wm + m * 16 + lr) * BK + (lq << 3));
#pragma unroll
    for (int n = 0; n < 4; ++n)
      bv[n] = *(const bf16x8*)(Bs + (wn + n * 16 + lr) * BK + (lq << 3));
#pragma unroll
    for (int m = 0; m < 4; ++m)
#pragma unroll
      for (int n = 0; n < 4; ++n)
        acc[m][n] = __builtin_amdgcn_mfma_f32_16x16x32_bf16(av[m], bv[n], acc[m][n], 0, 0, 0);
  }
#pragma unroll
  for (int m = 0; m < 4; ++m) {
#pragma unroll
    for (int n = 0; n < 4; ++n) {
      const int cc = col0 + n * 16 + lr;
      float bb = 0.0f;
      if constexpr (MODE == 0) bb = bias[cc];
#pragma unroll
      for (int e = 0; e < 4; ++e) {
        const int rr = row0 + m * 16 + (lq << 2) + e;
        if constexpr (MODE == 0) {
          Hout[(long)rr * N + cc] = f2bf(gelu_f(acc[m][n][e] + bb));
        } else {
          Pp[(long)z * pstride + (long)rr * N + cc] = acc[m][n][e];
        }
      }
    }
  }
}

// ---------------- reduce 2 split-K partials + bias, scatter to out ----------------
__global__ __launch_bounds__(256) void reduce_kernel(
    const float* __restrict__ Pp, const float* __restrict__ bias,
    const int* __restrict__ idx, const int* __restrict__ counts, const int eidx,
    float* __restrict__ out, const int D, const long pstride) {
  int M = counts[eidx];
  if (M > CAP) M = CAP;
  const long total = (long)M * (D >> 2);
  long i = blockIdx.x * 256L + threadIdx.x;
  const long stride = (long)gridDim.x * 256L;
  for (; i < total; i += stride) {
    const long e = i << 2;
    const int r = (int)(e / D);
    const int d = (int)(e - (long)r * D);
    const float4 a = *(const float4*)(Pp + e);
    const float4 b = *(const float4*)(Pp + pstride + e);
    const float4 bb = *(const float4*)(bias + d);
    float4 o;
    o.x = a.x + b.x + bb.x;
    o.y = a.y + b.y + bb.y;
    o.z = a.z + b.z + bb.z;
    o.w = a.w + b.w + bb.w;
    *(float4*)(out + (long)idx[r] * D + d) = o;
  }
}

extern "C" void kernel_launch(void* const* d_in, const int* in_sizes, int n_in,
                              void* d_out, int out_size, void* d_ws, size_t ws_size,
                              hipStream_t stream) {
  const float* x   = (const float*)d_in[0];
  const void* mask = d_in[1];
  const float* wfs = (const float*)d_in[2];
  const float* bfs = (const float*)d_in[3];
  const float* wps = (const float*)d_in[4];
  const float* bps = (const float*)d_in[5];
  const float* wfb = (const float*)d_in[6];
  const float* bfb = (const float*)d_in[7];
  const float* wpb = (const float*)d_in[8];
  const float* bpb = (const float*)d_in[9];
  float* out = (float*)d_out;

  const int n_tok = in_sizes[1];            // 8192
  const int D  = in_sizes[0] / n_tok;       // 1024
  const int Fs = in_sizes[3];               // 4096
  const int Fb = in_sizes[7];               // 16384
  const int SLAB = Fs;                      // 4096
  const int NSL = Fb / SLAB;                // 4

  char* ws = (char*)d_ws;
  size_t off = 0;
  auto alloc = [&](size_t b) { void* p = ws + off; off += (b + 255) & ~(size_t)255; return p; };

  int* idx_s  = (int*)alloc((size_t)n_tok * 4);
  int* idx_b  = (int*)alloc((size_t)n_tok * 4);
  int* counts = (int*)alloc(256);
  unsigned short* xg = (unsigned short*)alloc((size_t)n_tok * D * 2);
  const size_t fixed = off;

  // tiers: prefer preconverting both weight sets; fall back to fp32-staging paths
  const size_t hbytes = (size_t)CAP * SLAB * 2;          // 37.75 MB
  const size_t pbytes = (size_t)2 * CAP * D * 4;         // 37.75 MB
  int preS = 0, preB = 0;
  {
    const size_t wS = 2 * (size_t)Fs * D * 2 + 512;
    const size_t wB = 2 * (size_t)Fb * D * 2 + 512;
    if (fixed + wS + wB + hbytes + pbytes + 4096 <= ws_size) { preS = 1; preB = 1; }
    else if (fixed + wB + hbytes + pbytes + 4096 <= ws_size) { preB = 1; }
  }
  unsigned short* wfs_bf = preS ? (unsigned short*)alloc((size_t)Fs * D * 2) : nullptr;
  unsigned short* wps_bf = preS ? (unsigned short*)alloc((size_t)Fs * D * 2) : nullptr;
  unsigned short* wfb_bf = preB ? (unsigned short*)alloc((size_t)Fb * D * 2) : nullptr;
  unsigned short* wpb_bf = preB ? (unsigned short*)alloc((size_t)Fb * D * 2) : nullptr;
  unsigned short* Hbuf = (unsigned short*)alloc(hbytes);
  float* Pp = (float*)alloc(pbytes);
  const long pstride = (long)CAP * D;

  route_kernel<<<dim3(1), dim3(256), 0, stream>>>(mask, n_tok, idx_s, idx_b, counts);
  gather_cvt_kernel<<<dim3(4096), dim3(256), 0, stream>>>(
      x, idx_s, idx_b, counts, xg, n_tok, D);
  auto cvtl = [&](const float* src, unsigned short* dst, size_t n) {
    int n4 = (int)(n >> 2);
    int g = (n4 + 255) / 256; if (g > 2048) g = 2048;
    cvt_kernel<<<dim3(g), dim3(256), 0, stream>>>(src, dst, n4);
  };
  if (preS) { cvtl(wfs, wfs_bf, (size_t)Fs * D); cvtl(wps, wps_bf, (size_t)Fs * D); }
  if (preB) { cvtl(wfb, wfb_bf, (size_t)Fb * D); cvtl(wpb, wpb_bf, (size_t)Fb * D); }

  const dim3 blk(256);
  const dim3 gfc(SLAB / BN, GBM, 1);        // (32, 36)
  const dim3 gpr(D / BN, GBM, 2);           // (8, 36, 2)

  // ---- small expert (eidx 0, 1 slab) ----
  if (preS) {
    gemm_kernel<1, 0><<<gfc, blk, 0, stream>>>(
        xg, wfs_bf, bfs, Hbuf, nullptr, counts, 0, 0, SLAB, D, D, D, 0);
    gemm_kernel<1, 1><<<gpr, blk, 0, stream>>>(
        Hbuf, wps_bf, nullptr, nullptr, Pp, counts, 0, 0, D, SLAB, Fs, SLAB / 2, pstride);
  } else {
    gemm_kernel<0, 0><<<gfc, blk, 0, stream>>>(
        xg, wfs, bfs, Hbuf, nullptr, counts, 0, 0, SLAB, D, D, D, 0);
    gemm_kernel<0, 1><<<gpr, blk, 0, stream>>>(
        Hbuf, wps, nullptr, nullptr, Pp, counts, 0, 0, D, SLAB, Fs, SLAB / 2, pstride);
  }
  reduce_kernel<<<dim3(1024), blk, 0, stream>>>(
      Pp, bps, idx_s, counts, 0, out, D, pstride);

  // ---- big expert (eidx 1, NSL slabs) ----
  for (int s = 0; s < NSL; ++s) {
    const size_t bro = (size_t)s * SLAB * D;   // fc B row offset (elements)
    if (preB) {
      gemm_kernel<1, 0><<<gfc, blk, 0, stream>>>(
          xg, wfb_bf + bro, bfb + s * SLAB, Hbuf, nullptr, counts, 1, 1,
          SLAB, D, D, D, 0);
      if (s == 0)
        gemm_kernel<1, 1><<<gpr, blk, 0, stream>>>(
            Hbuf, wpb_bf + s * SLAB, nullptr, nullptr, Pp, counts, 1, 0,
            D, SLAB, Fb, SLAB / 2, pstride);
      else
        gemm_kernel<1, 2><<<gpr, blk, 0, stream>>>(
            Hbuf, wpb_bf + s * SLAB, nullptr, nullptr, Pp, counts, 1, 0,
            D, SLAB, Fb, SLAB / 2, pstride);
    } else {
      gemm_kernel<0, 0><<<gfc, blk, 0, stream>>>(
          xg, wfb + bro, bfb + s * SLAB, Hbuf, nullptr, counts, 1, 1,
          SLAB, D, D, D, 0);
      if (s == 0)
        gemm_kernel<0, 1><<<gpr, blk, 0, stream>>>(
            Hbuf, wpb + s * SLAB, nullptr, nullptr, Pp, counts, 1, 0,
            D, SLAB, Fb, SLAB / 2, pstride);
      else
        gemm_kernel<0, 2><<<gpr, blk, 0, stream>>>(
            Hbuf, wpb + s * SLAB, nullptr, nullptr, Pp, counts, 1, 0,
            D, SLAB, Fb, SLAB / 2, pstride);
    }
  }
  reduce_kernel<<<dim3(1024), blk, 0, stream>>>(
      Pp, bpb, idx_b, counts, 1, out, D, pstride);
}

// Round 7
// 756.196 us; speedup vs baseline: 1.4301x; 1.0514x over previous
//
#include <hip/hip_runtime.h>
#include <hip/hip_bf16.h>

typedef __attribute__((ext_vector_type(4))) float f32x4;
typedef __attribute__((ext_vector_type(8))) short bf16x8;

#define BM 128
#define BN 128
#define BK 32
#define CAP 4608            // token capacity per expert (+11 sigma over 4096)
#define GBM (CAP / BM)      // 36

__device__ __forceinline__ unsigned short f2bf(float f) {
  unsigned int u = __float_as_uint(f);
  u = (u + 0x7FFFu + ((u >> 16) & 1u)) >> 16;
  return (unsigned short)u;
}

// tanh-form gelu; |gelu_tanh - gelu_erf| < 3.2e-4 absolute — far under tolerance.
__device__ __forceinline__ float gelu_f(float h) {
  const float k0 = -1.5957691216057308f;
  const float k1 = -0.07135481627333355f;
  const float h2 = h * h;
  const float q = h * fmaf(k1, h2, k0);
  const float e = __expf(q);
  return h * __fdividef(1.0f, 1.0f + e);
}

__device__ __forceinline__ void gload16(const void* g, void* l) {
  __builtin_amdgcn_global_load_lds(
      (const __attribute__((address_space(1))) void*)g,
      (__attribute__((address_space(3))) void*)l,
      16, 0, 0);
}

// bijective XCD-aware swizzle (m204); nx = gridDim.x is a power of two (shift form)
__device__ __forceinline__ void xcd_swz(int& bn, int& bm, const int lognx) {
  const int nx = 1 << lognx, nwg = nx * gridDim.y;
  const int wg = blockIdx.x + nx * blockIdx.y;
  const int q = nwg >> 3, r = nwg & 7;
  const int xcd = wg & 7, pos = wg >> 3;
  const int base = xcd < r ? xcd * (q + 1) : r * (q + 1) + (xcd - r) * q;
  const int nid = base + pos;
  bn = nid & (nx - 1);
  bm = nid >> lognx;
}

// epilogue LDS scratch physical index (shorts): 80-short rows (16B-aligned),
// column XOR spread so the 4 lane-quads hit disjoint bank groups
__device__ __forceinline__ int epc(int lrow, int lcol) {
  return lrow * 80 + (lcol ^ (((lrow >> 2) & 3) << 4));
}

// ---------------- fp32 -> bf16 convert (weights) ----------------
__global__ __launch_bounds__(256) void cvt_kernel(const float* __restrict__ in,
                                                  unsigned short* __restrict__ out,
                                                  int n4) {
  int i = blockIdx.x * 256 + threadIdx.x;
  const int stride = gridDim.x * 256;
  for (; i < n4; i += stride) {
    const float4 v = ((const float4*)in)[i];
    ushort4 o;
    o.x = f2bf(v.x); o.y = f2bf(v.y); o.z = f2bf(v.z); o.w = f2bf(v.w);
    ((ushort4*)out)[i] = o;
  }
}

// ---------------- routing: compact token indices per expert ----------------
__global__ __launch_bounds__(256) void route_kernel(const void* __restrict__ mask,
                                                    int n_tok,
                                                    int* __restrict__ idx_s,
                                                    int* __restrict__ idx_b,
                                                    int* __restrict__ counts) {
  __shared__ int mode_sh;
  __shared__ int cs[256], cb[256];
  __shared__ int os[256], ob[256];
  const unsigned char* mb = (const unsigned char*)mask;
  const int* mi = (const int*)mask;
  const int tid = threadIdx.x;
  if (tid == 0) mode_sh = 0;
  __syncthreads();
  int found = 0;
  for (int i = tid; i < n_tok; i += 256)
    if ((i & 3) == 1 && mb[i]) found = 1;   // int32/fp32 bools have byte1 == 0
  if (found) atomicOr(&mode_sh, 1);
  __syncthreads();
  const int byte_mode = mode_sh;
  const int per = n_tok / 256;
  const int t0 = tid * per;
  for (int i = 0; i < per; ++i) { idx_s[t0 + i] = 0; idx_b[t0 + i] = 0; }
  int ls = 0, lb = 0;
  for (int i = 0; i < per; ++i) {
    const int m = byte_mode ? (mb[t0 + i] != 0) : (mi[t0 + i] != 0);
    ls += !m; lb += m;
  }
  cs[tid] = ls; cb[tid] = lb;
  __syncthreads();
  if (tid == 0) {
    int as = 0, ab = 0;
    for (int i = 0; i < 256; ++i) { os[i] = as; ob[i] = ab; as += cs[i]; ab += cb[i]; }
    counts[0] = as; counts[1] = ab;
  }
  __syncthreads();
  int ps = os[tid], pb = ob[tid];
  for (int i = 0; i < per; ++i) {
    const int m = byte_mode ? (mb[t0 + i] != 0) : (mi[t0 + i] != 0);
    if (m) idx_b[pb++] = t0 + i; else idx_s[ps++] = t0 + i;
  }
}

// ---------------- combined gather + cvt: xg[0:ns)=small tokens, xg[ns:8192)=big ----------------
__global__ __launch_bounds__(256) void gather_cvt_kernel(
    const float* __restrict__ x,
    const int* __restrict__ idx_s, const int* __restrict__ idx_b,
    const int* __restrict__ counts,
    unsigned short* __restrict__ xg,
    const int n_tok, const int D) {
  const int gpr = D >> 3;
  const int total = n_tok * gpr;
  const int c0 = counts[0];
  int g = blockIdx.x * 256 + threadIdx.x;
  const int stride = gridDim.x * 256;
  for (; g < total; g += stride) {
    const int r = g / gpr;
    const int c = (g - r * gpr) << 3;
    const int src = r < c0 ? idx_s[r] : idx_b[r - c0];
    const float4 v0 = *(const float4*)(x + (long)src * D + c);
    const float4 v1 = *(const float4*)(x + (long)src * D + c + 4);
    ushort4 a, b;
    a.x = f2bf(v0.x); a.y = f2bf(v0.y); a.z = f2bf(v0.z); a.w = f2bf(v0.w);
    b.x = f2bf(v1.x); b.y = f2bf(v1.y); b.z = f2bf(v1.z); b.w = f2bf(v1.w);
    unsigned short* dst = xg + (long)r * D + c;
    *(ushort4*)dst = a;
    *(ushort4*)(dst + 4) = b;
  }
}

// ---------------- unified GEMM: C = A @ B^T, pipelined double-buffered ----------------
// MODE 0: H[r][c] = bf16(gelu(acc + bias[c]))   (fc slab; grid.z=1), LDS-bounce stores
// MODE 1: Pp[z][r][c] = acc                      (proj slab 0; grid.z=2)
// MODE 2: Pp[z][r][c] += acc                     (proj slabs >0, C-in accumulate)
template <int BF16B, int MODE>
__global__ __launch_bounds__(256) void gemm_kernel(
    const unsigned short* __restrict__ A,
    const void* __restrict__ Bv,
    const float* __restrict__ bias,
    unsigned short* __restrict__ Hout,
    float* __restrict__ Pp,
    const int* __restrict__ counts, const int eidx, const int useAbase,
    const int lognx,
    const int N, const int astride, const int bstride,
    const int Kc, const long pstride) {
  __shared__ alignas(16) unsigned short As[2][BM * BK];
  __shared__ alignas(16) unsigned short Bs[2][BN * BK];
  const int M = counts[eidx];
  int bn, bm;
  xcd_swz(bn, bm, lognx);
  const int z = blockIdx.z;
  if (bm * BM >= M) return;
  const int abase = useAbase ? counts[0] : 0;
  const int tid = threadIdx.x, wid = tid >> 6, lane = tid & 63;
  const int lr = lane & 15, lq = lane >> 4;
  const int wm = (wid >> 1) << 6, wn = (wid & 1) << 6;
  const int row0 = bm * BM + wm, col0 = bn * BN + wn;
  // A staging: global_load_lds, 16B/lane, linear dest
  const int srow = (wid << 5) + (lane >> 2);
  const int scol = (lane & 3) << 3;
  const unsigned short* pA0 = A + (long)(abase + bm * BM + srow) * astride + scol;
  const unsigned short* pA1 = pA0 + (long)16 * astride;
  const int lAo0 = (wid << 5) * BK;
  const int lAo1 = lAo0 + 16 * BK;
  // B staging
  const unsigned short* pB0 = nullptr; const unsigned short* pB1 = nullptr;
  const float* pBf = nullptr;
  int brow = 0, bcol = 0;
  if constexpr (BF16B) {
    const unsigned short* B = (const unsigned short*)Bv;
    pB0 = B + (long)(bn * BN + srow) * bstride + scol;
    pB1 = pB0 + (long)16 * bstride;
  } else {
    const float* B = (const float*)Bv;
    brow = tid >> 3; bcol = (tid & 7) << 2;
    pBf = B + (long)(bn * BN + brow) * bstride + bcol;
  }
  const int kbeg = z * Kc;
  const int nt = Kc / BK;

  float4 vB[4];
  auto loadB = [&](int k0) {
#pragma unroll
    for (int j = 0; j < 4; ++j)
      vB[j] = *(const float4*)(pBf + (long)(j * 32) * bstride + k0);
  };
  auto writeB = [&](int b) {
#pragma unroll
    for (int j = 0; j < 4; ++j) {
      ushort4 o;
      o.x = f2bf(vB[j].x); o.y = f2bf(vB[j].y);
      o.z = f2bf(vB[j].z); o.w = f2bf(vB[j].w);
      *(ushort4*)(&Bs[b][(brow + j * 32) * BK + bcol]) = o;
    }
  };
  auto stage = [&](int b, int k0) {
    gload16(pA0 + k0, &As[b][lAo0]);
    gload16(pA1 + k0, &As[b][lAo1]);
    if constexpr (BF16B) {
      gload16(pB0 + k0, &Bs[b][lAo0]);
      gload16(pB1 + k0, &Bs[b][lAo1]);
    }
  };

  // prologue: stage tile 0
  if constexpr (!BF16B) loadB(kbeg);
  stage(0, kbeg);

  f32x4 acc[4][4];
  if constexpr (MODE == 2) {
#pragma unroll
    for (int m = 0; m < 4; ++m)
#pragma unroll
      for (int n = 0; n < 4; ++n) {
        const int cc = col0 + n * 16 + lr;
#pragma unroll
        for (int e = 0; e < 4; ++e) {
          const int rr = row0 + m * 16 + (lq << 2) + e;
          acc[m][n][e] = Pp[(long)z * pstride + (long)rr * N + cc];
        }
      }
  } else {
    const f32x4 zero = {0.0f, 0.0f, 0.0f, 0.0f};
#pragma unroll
    for (int m = 0; m < 4; ++m)
#pragma unroll
      for (int n = 0; n < 4; ++n) acc[m][n] = zero;
  }
  if constexpr (!BF16B) writeB(0);
  __syncthreads();

  // pipelined main loop: stage(t+1) overlaps compute(t); one barrier per step
  for (int t = 0; t < nt; ++t) {
    const int cur = t & 1;
    if (t + 1 < nt) {
      if constexpr (!BF16B) loadB(kbeg + (t + 1) * BK);
      stage(cur ^ 1, kbeg + (t + 1) * BK);
    }
    bf16x8 av[4], bv[4];
#pragma unroll
    for (int m = 0; m < 4; ++m)
      av[m] = *(const bf16x8*)(&As[cur][(wm + m * 16 + lr) * BK + (lq << 3)]);
#pragma unroll
    for (int n = 0; n < 4; ++n)
      bv[n] = *(const bf16x8*)(&Bs[cur][(wn + n * 16 + lr) * BK + (lq << 3)]);
#pragma unroll
    for (int m = 0; m < 4; ++m)
#pragma unroll
      for (int n = 0; n < 4; ++n)
        acc[m][n] = __builtin_amdgcn_mfma_f32_16x16x32_bf16(av[m], bv[n], acc[m][n], 0, 0, 0);
    if (t + 1 < nt) {
      if constexpr (!BF16B) writeB(cur ^ 1);
    }
    __syncthreads();   // drains vmcnt (stage t+1 done) + orders LDS for next step
  }

  if constexpr (MODE == 0) {
    // LDS-bounce epilogue: per-wave scratch in the (now free) staging buffers,
    // scattered 2B stores -> 8 coalesced 16B stores per lane
    unsigned short* eb =
        (wid < 2 ? (unsigned short*)As : (unsigned short*)Bs) + (wid & 1) * 2560;
#pragma unroll
    for (int half = 0; half < 2; ++half) {
#pragma unroll
      for (int mm = 0; mm < 2; ++mm) {
        const int m = half * 2 + mm;
#pragma unroll
        for (int n = 0; n < 4; ++n) {
          const int lcol = n * 16 + lr;
          const float bb = bias[col0 + lcol];
#pragma unroll
          for (int e = 0; e < 4; ++e) {
            const int lrow = mm * 16 + (lq << 2) + e;
            eb[epc(lrow, lcol)] = f2bf(gelu_f(acc[m][n][e] + bb));
          }
        }
      }
#pragma unroll
      for (int j = 0; j < 4; ++j) {
        const int lrow = j * 8 + (lane >> 3);
        const int lcol = (lane & 7) * 8;
        const bf16x8 v = *(const bf16x8*)(&eb[epc(lrow, lcol)]);
        *(bf16x8*)(Hout + (long)(row0 + half * 32 + lrow) * N + col0 + lcol) = v;
      }
    }
  } else {
#pragma unroll
    for (int m = 0; m < 4; ++m)
#pragma unroll
      for (int n = 0; n < 4; ++n) {
        const int cc = col0 + n * 16 + lr;
#pragma unroll
        for (int e = 0; e < 4; ++e) {
          const int rr = row0 + m * 16 + (lq << 2) + e;
          Pp[(long)z * pstride + (long)rr * N + cc] = acc[m][n][e];
        }
      }
  }
}

// ---------------- reduce 2 split-K partials + bias, scatter to out ----------------
__global__ __launch_bounds__(256) void reduce_kernel(
    const float* __restrict__ Pp, const float* __restrict__ bias,
    const int* __restrict__ idx, const int* __restrict__ counts, const int eidx,
    float* __restrict__ out, const int D, const long pstride) {
  int M = counts[eidx];
  if (M > CAP) M = CAP;
  const long total = (long)M * (D >> 2);
  long i = blockIdx.x * 256L + threadIdx.x;
  const long stride = (long)gridDim.x * 256L;
  for (; i < total; i += stride) {
    const long e = i << 2;
    const int r = (int)(e / D);
    const int d = (int)(e - (long)r * D);
    const float4 a = *(const float4*)(Pp + e);
    const float4 b = *(const float4*)(Pp + pstride + e);
    const float4 bb = *(const float4*)(bias + d);
    float4 o;
    o.x = a.x + b.x + bb.x;
    o.y = a.y + b.y + bb.y;
    o.z = a.z + b.z + bb.z;
    o.w = a.w + b.w + bb.w;
    *(float4*)(out + (long)idx[r] * D + d) = o;
  }
}

extern "C" void kernel_launch(void* const* d_in, const int* in_sizes, int n_in,
                              void* d_out, int out_size, void* d_ws, size_t ws_size,
                              hipStream_t stream) {
  const float* x   = (const float*)d_in[0];
  const void* mask = d_in[1];
  const float* wfs = (const float*)d_in[2];
  const float* bfs = (const float*)d_in[3];
  const float* wps = (const float*)d_in[4];
  const float* bps = (const float*)d_in[5];
  const float* wfb = (const float*)d_in[6];
  const float* bfb = (const float*)d_in[7];
  const float* wpb = (const float*)d_in[8];
  const float* bpb = (const float*)d_in[9];
  float* out = (float*)d_out;

  const int n_tok = in_sizes[1];            // 8192
  const int D  = in_sizes[0] / n_tok;       // 1024
  const int Fs = in_sizes[3];               // 4096
  const int Fb = in_sizes[7];               // 16384
  const int SLAB = Fs;                      // 4096
  const int NSL = Fb / SLAB;                // 4

  char* ws = (char*)d_ws;
  size_t off = 0;
  auto alloc = [&](size_t b) { void* p = ws + off; off += (b + 255) & ~(size_t)255; return p; };

  int* idx_s  = (int*)alloc((size_t)n_tok * 4);
  int* idx_b  = (int*)alloc((size_t)n_tok * 4);
  int* counts = (int*)alloc(256);
  unsigned short* xg = (unsigned short*)alloc((size_t)n_tok * D * 2);
  const size_t fixed = off;

  // tiers: prefer preconverting both weight sets; fall back to fp32-staging paths
  const size_t hbytes = (size_t)CAP * SLAB * 2;          // 37.75 MB
  const size_t pbytes = (size_t)2 * CAP * D * 4;         // 37.75 MB
  int preS = 0, preB = 0;
  {
    const size_t wS = 2 * (size_t)Fs * D * 2 + 512;
    const size_t wB = 2 * (size_t)Fb * D * 2 + 512;
    if (fixed + wS + wB + hbytes + pbytes + 4096 <= ws_size) { preS = 1; preB = 1; }
    else if (fixed + wB + hbytes + pbytes + 4096 <= ws_size) { preB = 1; }
  }
  unsigned short* wfs_bf = preS ? (unsigned short*)alloc((size_t)Fs * D * 2) : nullptr;
  unsigned short* wps_bf = preS ? (unsigned short*)alloc((size_t)Fs * D * 2) : nullptr;
  unsigned short* wfb_bf = preB ? (unsigned short*)alloc((size_t)Fb * D * 2) : nullptr;
  unsigned short* wpb_bf = preB ? (unsigned short*)alloc((size_t)Fb * D * 2) : nullptr;
  unsigned short* Hbuf = (unsigned short*)alloc(hbytes);
  float* Pp = (float*)alloc(pbytes);
  const long pstride = (long)CAP * D;

  route_kernel<<<dim3(1), dim3(256), 0, stream>>>(mask, n_tok, idx_s, idx_b, counts);
  gather_cvt_kernel<<<dim3(4096), dim3(256), 0, stream>>>(
      x, idx_s, idx_b, counts, xg, n_tok, D);
  auto cvtl = [&](const float* src, unsigned short* dst, size_t n) {
    int n4 = (int)(n >> 2);
    int g = (n4 + 255) / 256; if (g > 2048) g = 2048;
    cvt_kernel<<<dim3(g), dim3(256), 0, stream>>>(src, dst, n4);
  };
  if (preS) { cvtl(wfs, wfs_bf, (size_t)Fs * D); cvtl(wps, wps_bf, (size_t)Fs * D); }
  if (preB) { cvtl(wfb, wfb_bf, (size_t)Fb * D); cvtl(wpb, wpb_bf, (size_t)Fb * D); }

  const dim3 blk(256);
  const dim3 gfc(SLAB / BN, GBM, 1);        // (32, 36), lognx=5
  const dim3 gpr(D / BN, GBM, 2);           // (8, 36, 2), lognx=3

  // ---- small expert (eidx 0, 1 slab) ----
  if (preS) {
    gemm_kernel<1, 0><<<gfc, blk, 0, stream>>>(
        xg, wfs_bf, bfs, Hbuf, nullptr, counts, 0, 0, 5, SLAB, D, D, D, 0);
    gemm_kernel<1, 1><<<gpr, blk, 0, stream>>>(
        Hbuf, wps_bf, nullptr, nullptr, Pp, counts, 0, 0, 3, D, SLAB, Fs, SLAB / 2, pstride);
  } else {
    gemm_kernel<0, 0><<<gfc, blk, 0, stream>>>(
        xg, wfs, bfs, Hbuf, nullptr, counts, 0, 0, 5, SLAB, D, D, D, 0);
    gemm_kernel<0, 1><<<gpr, blk, 0, stream>>>(
        Hbuf, wps, nullptr, nullptr, Pp, counts, 0, 0, 3, D, SLAB, Fs, SLAB / 2, pstride);
  }
  reduce_kernel<<<dim3(1024), blk, 0, stream>>>(
      Pp, bps, idx_s, counts, 0, out, D, pstride);

  // ---- big expert (eidx 1, NSL slabs) ----
  for (int s = 0; s < NSL; ++s) {
    const size_t bro = (size_t)s * SLAB * D;   // fc B row offset (elements)
    if (preB) {
      gemm_kernel<1, 0><<<gfc, blk, 0, stream>>>(
          xg, wfb_bf + bro, bfb + s * SLAB, Hbuf, nullptr, counts, 1, 1, 5,
          SLAB, D, D, D, 0);
      if (s == 0)
        gemm_kernel<1, 1><<<gpr, blk, 0, stream>>>(
            Hbuf, wpb_bf + s * SLAB, nullptr, nullptr, Pp, counts, 1, 0, 3,
            D, SLAB, Fb, SLAB / 2, pstride);
      else
        gemm_kernel<1, 2><<<gpr, blk, 0, stream>>>(
            Hbuf, wpb_bf + s * SLAB, nullptr, nullptr, Pp, counts, 1, 0, 3,
            D, SLAB, Fb, SLAB / 2, pstride);
    } else {
      gemm_kernel<0, 0><<<gfc, blk, 0, stream>>>(
          xg, wfb + bro, bfb + s * SLAB, Hbuf, nullptr, counts, 1, 1, 5,
          SLAB, D, D, D, 0);
      if (s == 0)
        gemm_kernel<0, 1><<<gpr, blk, 0, stream>>>(
            Hbuf, wpb + s * SLAB, nullptr, nullptr, Pp, counts, 1, 0, 3,
            D, SLAB, Fb, SLAB / 2, pstride);
      else
        gemm_kernel<0, 2><<<gpr, blk, 0, stream>>>(
            Hbuf, wpb + s * SLAB, nullptr, nullptr, Pp, counts, 1, 0, 3,
            D, SLAB, Fb, SLAB / 2, pstride);
    }
  }
  reduce_kernel<<<dim3(1024), blk, 0, stream>>>(
      Pp, bpb, idx_b, counts, 1, out, D, pstride);
}